// Round 1
// baseline (6793.242 us; speedup 1.0000x reference)
//
#include <hip/hip_runtime.h>
#include <math.h>

#define B_    128
#define T_ENC 40
#define T_DEC 27
#define HID_  512
#define G3_   1536
#define EMB_  1024
#define V_    20000

__device__ __forceinline__ float sigmoidf_(float x) { return 1.f / (1.f + expf(-x)); }

// ---------------- gather decoder word embeddings ----------------
// words[m = b*27+t][:] = E[target[b*28+t]][:]
__global__ __launch_bounds__(128) void k_gather(const int* __restrict__ target,
                                                const float* __restrict__ E,
                                                float* __restrict__ words) {
  int m = blockIdx.x;                 // 0..B*T_DEC-1
  int b = m / T_DEC, t = m % T_DEC;
  int idx = target[b * 28 + t];
  const float4* src = reinterpret_cast<const float4*>(E + (size_t)idx * HID_);
  float4* dst = reinterpret_cast<float4*>(words + (size_t)m * HID_);
  dst[threadIdx.x] = src[threadIdx.x];
}

// ---------------- generic fp32 GEMM: C[m][n] = sum_k A[m][k]*B[n][boff+k] + bias[n] ----------------
// 128x128 tile, BK=16, 256 threads, 8x8 per thread. M must be multiple of 128, K of 16, N of 8.
__global__ __launch_bounds__(256) void k_gemm(const float* __restrict__ A, int lda,
                                              const float* __restrict__ Bm, int ldb, int boff,
                                              const float* __restrict__ bias,
                                              float* __restrict__ C, int ldc,
                                              int N, int K) {
  __shared__ float As[16][128];
  __shared__ float Bs[16][128];
  const int tid = threadIdx.x;
  const int m0 = blockIdx.y * 128;
  const int n0 = blockIdx.x * 128;
  const int tx = tid & 15, ty = tid >> 4;
  float acc[8][8];
#pragma unroll
  for (int i = 0; i < 8; ++i)
#pragma unroll
    for (int j = 0; j < 8; ++j) acc[i][j] = 0.f;

  for (int k0 = 0; k0 < K; k0 += 16) {
#pragma unroll
    for (int i = 0; i < 2; ++i) {
      int v = tid * 2 + i;            // 0..511 (512 float4 per tile)
      int row = v >> 2;               // 0..127
      int kv = (v & 3) << 2;          // 0,4,8,12
      float4 a4 = *reinterpret_cast<const float4*>(&A[(size_t)(m0 + row) * lda + k0 + kv]);
      As[kv + 0][row] = a4.x; As[kv + 1][row] = a4.y; As[kv + 2][row] = a4.z; As[kv + 3][row] = a4.w;
      int nr = n0 + row;
      float4 b4 = make_float4(0.f, 0.f, 0.f, 0.f);
      if (nr < N) b4 = *reinterpret_cast<const float4*>(&Bm[(size_t)nr * ldb + boff + k0 + kv]);
      Bs[kv + 0][row] = b4.x; Bs[kv + 1][row] = b4.y; Bs[kv + 2][row] = b4.z; Bs[kv + 3][row] = b4.w;
    }
    __syncthreads();
#pragma unroll
    for (int kk = 0; kk < 16; ++kk) {
      float a[8], bb[8];
      *reinterpret_cast<float4*>(&a[0]) = *reinterpret_cast<const float4*>(&As[kk][ty * 8]);
      *reinterpret_cast<float4*>(&a[4]) = *reinterpret_cast<const float4*>(&As[kk][ty * 8 + 4]);
      *reinterpret_cast<float4*>(&bb[0]) = *reinterpret_cast<const float4*>(&Bs[kk][tx * 8]);
      *reinterpret_cast<float4*>(&bb[4]) = *reinterpret_cast<const float4*>(&Bs[kk][tx * 8 + 4]);
#pragma unroll
      for (int i = 0; i < 8; ++i)
#pragma unroll
        for (int j = 0; j < 8; ++j) acc[i][j] += a[i] * bb[j];
    }
    __syncthreads();
  }
#pragma unroll
  for (int i = 0; i < 8; ++i) {
    int m = m0 + ty * 8 + i;
    int n = n0 + tx * 8;
    if (n < N) {                       // N % 8 == 0 -> whole 8-group valid
      float* cp = &C[(size_t)m * ldc + n];
#pragma unroll
      for (int j = 0; j < 8; ++j) cp[j] = acc[i][j] + bias[n + j];
    }
  }
}

// ---------------- step kernel A ----------------
// part0 (blockIdx.z==0): gh1 = h1_old @ W_hh1^T (3 gates) -> combine with gi1 -> h1_new
// part1 (blockIdx.z==1): gh2 = h2_old @ W_hh2^T + b_hh2 -> stored raw
// grid (8 j-tiles, 8 b-tiles, 2), 256 threads; per block: 16 b x 64 j x 3 gates, K=512.
__global__ __launch_bounds__(256) void k_step_a(
    const float* __restrict__ h1_old, const float* __restrict__ h2_old,
    const float* __restrict__ gi1base, int gi1_stride,
    const float* __restrict__ W_hh1, const float* __restrict__ b_hh1,
    const float* __restrict__ W_hh2, const float* __restrict__ b_hh2,
    float* __restrict__ h1_new, float* __restrict__ gh2) {
  const int part = blockIdx.z;
  const float* __restrict__ h = part ? h2_old : h1_old;
  const float* __restrict__ W = part ? W_hh2 : W_hh1;
  __shared__ float As[32][16];      // [k][b]
  __shared__ float Ws[3][32][64];   // [g][k][j]
  const int tid = threadIdx.x;
  const int tx = tid & 31, ty = tid >> 5;
  const int b0 = blockIdx.y * 16;
  const int j0 = blockIdx.x * 64;
  float acc[3][2][2];
#pragma unroll
  for (int g = 0; g < 3; ++g)
#pragma unroll
    for (int i = 0; i < 2; ++i) { acc[g][i][0] = 0.f; acc[g][i][1] = 0.f; }

  for (int k0 = 0; k0 < HID_; k0 += 32) {
    {
      int v = tid * 2;                // 0..510, 512 floats total
      int row = v >> 5;               // 0..15
      int kk = v & 31;                // even
      float2 a2 = *reinterpret_cast<const float2*>(&h[(size_t)(b0 + row) * HID_ + k0 + kk]);
      As[kk][row] = a2.x; As[kk + 1][row] = a2.y;
    }
#pragma unroll
    for (int i = 0; i < 6; ++i) {
      int v = (tid + i * 256) * 4;    // 6144 floats as 1536 float4
      int row = v >> 5;               // 0..191
      int kk = v & 31;                // 0,4,...,28
      int g = row >> 6, j = row & 63;
      float4 w4 = *reinterpret_cast<const float4*>(&W[(size_t)(g * HID_ + j0 + j) * HID_ + k0 + kk]);
      Ws[g][kk + 0][j] = w4.x; Ws[g][kk + 1][j] = w4.y; Ws[g][kk + 2][j] = w4.z; Ws[g][kk + 3][j] = w4.w;
    }
    __syncthreads();
#pragma unroll
    for (int kk = 0; kk < 32; ++kk) {
      float2 a = *reinterpret_cast<const float2*>(&As[kk][ty * 2]);
#pragma unroll
      for (int g = 0; g < 3; ++g) {
        float2 w = *reinterpret_cast<const float2*>(&Ws[g][kk][tx * 2]);
        acc[g][0][0] += a.x * w.x; acc[g][0][1] += a.x * w.y;
        acc[g][1][0] += a.y * w.x; acc[g][1][1] += a.y * w.y;
      }
    }
    __syncthreads();
  }
#pragma unroll
  for (int bi = 0; bi < 2; ++bi) {
#pragma unroll
    for (int ji = 0; ji < 2; ++ji) {
      int b = b0 + ty * 2 + bi;
      int j = j0 + tx * 2 + ji;
      if (part == 0) {
        float gr = acc[0][bi][ji] + b_hh1[j];
        float gz = acc[1][bi][ji] + b_hh1[HID_ + j];
        float gn = acc[2][bi][ji] + b_hh1[2 * HID_ + j];
        const float* gi = gi1base + (size_t)b * gi1_stride;
        float r = sigmoidf_(gi[j] + gr);
        float z = sigmoidf_(gi[HID_ + j] + gz);
        float n = tanhf(gi[2 * HID_ + j] + r * gn);
        float hp = h1_old[(size_t)b * HID_ + j];
        h1_new[(size_t)b * HID_ + j] = (1.f - z) * n + z * hp;
      } else {
        gh2[(size_t)b * G3_ + j]            = acc[0][bi][ji] + b_hh2[j];
        gh2[(size_t)b * G3_ + HID_ + j]     = acc[1][bi][ji] + b_hh2[HID_ + j];
        gh2[(size_t)b * G3_ + 2 * HID_ + j] = acc[2][bi][ji] + b_hh2[2 * HID_ + j];
      }
    }
  }
}

// ---------------- step kernel B ----------------
// gi2 = h1_new @ W_ih2[:, :512]^T (3 gates) + gi2base; combine with gh2 -> h2_new (+h2seq)
__global__ __launch_bounds__(256) void k_step_b(
    const float* __restrict__ h1n, const float* __restrict__ h2_old,
    const float* __restrict__ gh2,
    const float* __restrict__ W_ih2,
    const float* __restrict__ gi2base, int gi2_stride,
    float* __restrict__ h2_new, float* __restrict__ seq) {
  __shared__ float As[32][16];
  __shared__ float Ws[3][32][64];
  const int tid = threadIdx.x;
  const int tx = tid & 31, ty = tid >> 5;
  const int b0 = blockIdx.y * 16;
  const int j0 = blockIdx.x * 64;
  float acc[3][2][2];
#pragma unroll
  for (int g = 0; g < 3; ++g)
#pragma unroll
    for (int i = 0; i < 2; ++i) { acc[g][i][0] = 0.f; acc[g][i][1] = 0.f; }

  for (int k0 = 0; k0 < HID_; k0 += 32) {
    {
      int v = tid * 2;
      int row = v >> 5;
      int kk = v & 31;
      float2 a2 = *reinterpret_cast<const float2*>(&h1n[(size_t)(b0 + row) * HID_ + k0 + kk]);
      As[kk][row] = a2.x; As[kk + 1][row] = a2.y;
    }
#pragma unroll
    for (int i = 0; i < 6; ++i) {
      int v = (tid + i * 256) * 4;
      int row = v >> 5;
      int kk = v & 31;
      int g = row >> 6, j = row & 63;
      float4 w4 = *reinterpret_cast<const float4*>(&W_ih2[(size_t)(g * HID_ + j0 + j) * EMB_ + k0 + kk]);
      Ws[g][kk + 0][j] = w4.x; Ws[g][kk + 1][j] = w4.y; Ws[g][kk + 2][j] = w4.z; Ws[g][kk + 3][j] = w4.w;
    }
    __syncthreads();
#pragma unroll
    for (int kk = 0; kk < 32; ++kk) {
      float2 a = *reinterpret_cast<const float2*>(&As[kk][ty * 2]);
#pragma unroll
      for (int g = 0; g < 3; ++g) {
        float2 w = *reinterpret_cast<const float2*>(&Ws[g][kk][tx * 2]);
        acc[g][0][0] += a.x * w.x; acc[g][0][1] += a.x * w.y;
        acc[g][1][0] += a.y * w.x; acc[g][1][1] += a.y * w.y;
      }
    }
    __syncthreads();
  }
#pragma unroll
  for (int bi = 0; bi < 2; ++bi) {
#pragma unroll
    for (int ji = 0; ji < 2; ++ji) {
      int b = b0 + ty * 2 + bi;
      int j = j0 + tx * 2 + ji;
      const float* gi = gi2base + (size_t)b * gi2_stride;
      float hr = gh2[(size_t)b * G3_ + j];
      float hz = gh2[(size_t)b * G3_ + HID_ + j];
      float hn = gh2[(size_t)b * G3_ + 2 * HID_ + j];
      float r = sigmoidf_(gi[j] + acc[0][bi][ji] + hr);
      float z = sigmoidf_(gi[HID_ + j] + acc[1][bi][ji] + hz);
      float n = tanhf(gi[2 * HID_ + j] + acc[2][bi][ji] + r * hn);
      float hp = h2_old[(size_t)b * HID_ + j];
      float hv = (1.f - z) * n + z * hp;
      h2_new[(size_t)b * HID_ + j] = hv;
      if (seq) seq[(size_t)b * (T_DEC * HID_) + j] = hv;
    }
  }
}

// ---------------- log-softmax over rows of 20000 (in place on d_out) ----------------
__global__ __launch_bounds__(256) void k_logsoftmax(float* __restrict__ out) {
  float* row = out + (size_t)blockIdx.x * V_;
  const int tid = threadIdx.x;
  float mx = -INFINITY, s = 0.f;
  for (int i = tid; i < V_; i += 256) {
    float x = row[i];
    if (x > mx) { s = s * expf(mx - x) + 1.f; mx = x; }
    else        { s += expf(x - mx); }
  }
#pragma unroll
  for (int o = 1; o < 64; o <<= 1) {
    float omx = __shfl_xor(mx, o);
    float os  = __shfl_xor(s, o);
    float M = fmaxf(mx, omx);
    s = s * expf(mx - M) + os * expf(omx - M);
    mx = M;
  }
  __shared__ float smx[4], ss[4];
  int wid = tid >> 6, lane = tid & 63;
  if (lane == 0) { smx[wid] = mx; ss[wid] = s; }
  __syncthreads();
  if (tid == 0) {
    float M = smx[0]; float S = ss[0];
#pragma unroll
    for (int w = 1; w < 4; ++w) {
      float M2 = fmaxf(M, smx[w]);
      S = S * expf(M - M2) + ss[w] * expf(smx[w] - M2);
      M = M2;
    }
    ss[0] = logf(S) + M;
  }
  __syncthreads();
  float lse = ss[0];
  for (int i = tid; i < V_; i += 256) row[i] -= lse;
}

// ---------------- host launch ----------------
extern "C" void kernel_launch(void* const* d_in, const int* in_sizes, int n_in,
                              void* d_out, int out_size, void* d_ws, size_t ws_size,
                              hipStream_t stream) {
  const float* input = (const float*)d_in[0];
  const int*   target = (const int*)d_in[1];
  const float* W_ih1 = (const float*)d_in[2];
  const float* W_hh1 = (const float*)d_in[3];
  const float* b_ih1 = (const float*)d_in[4];
  const float* b_hh1 = (const float*)d_in[5];
  const float* W_ih2 = (const float*)d_in[6];
  const float* W_hh2 = (const float*)d_in[7];
  const float* b_ih2 = (const float*)d_in[8];
  const float* b_hh2 = (const float*)d_in[9];
  const float* E     = (const float*)d_in[10];
  const float* W_out = (const float*)d_in[11];
  const float* b_out = (const float*)d_in[12];
  float* out = (float*)d_out;

  float* ws = (float*)d_ws;
  float* G1    = ws; ws += (size_t)B_ * T_ENC * G3_;   // enc input gates (incl b_ih1), row m=b*40+t
  float* GW    = ws; ws += (size_t)B_ * T_DEC * G3_;   // dec word gates (incl b_ih2), row m=b*27+t
  float* words = ws; ws += (size_t)B_ * T_DEC * HID_;  // gathered embeddings, row m=b*27+t
  float* h2seq = ws; ws += (size_t)B_ * T_DEC * HID_;  // decoder h2 outputs, [b][t][:]
  float* h1buf[2]; float* h2buf[2];
  h1buf[0] = ws; ws += B_ * HID_;
  h2buf[0] = ws; ws += B_ * HID_;    // contiguous with h1buf[0] for single memset
  h1buf[1] = ws; ws += B_ * HID_;
  h2buf[1] = ws; ws += B_ * HID_;
  float* gh2 = ws; ws += (size_t)B_ * G3_;

  hipMemsetAsync(h1buf[0], 0, (size_t)2 * B_ * HID_ * sizeof(float), stream);

  k_gather<<<B_ * T_DEC, 128, 0, stream>>>(target, E, words);
  // G1 = input @ W_ih1^T + b_ih1   (5120 x 1536 x 1024)
  k_gemm<<<dim3(G3_ / 128, (B_ * T_ENC) / 128), 256, 0, stream>>>(
      input, EMB_, W_ih1, EMB_, 0, b_ih1, G1, G3_, G3_, EMB_);
  // GW = words @ W_ih2[:,512:]^T + b_ih2   (3456 x 1536 x 512)
  k_gemm<<<dim3(G3_ / 128, (B_ * T_DEC) / 128), 256, 0, stream>>>(
      words, HID_, W_ih2, EMB_, HID_, b_ih2, GW, G3_, G3_, HID_);

  int cur = 0;
  for (int t = 0; t < T_ENC; ++t) {
    k_step_a<<<dim3(8, 8, 2), 256, 0, stream>>>(
        h1buf[cur], h2buf[cur], G1 + (size_t)t * G3_, T_ENC * G3_,
        W_hh1, b_hh1, W_hh2, b_hh2, h1buf[1 - cur], gh2);
    k_step_b<<<dim3(8, 8), 256, 0, stream>>>(
        h1buf[1 - cur], h2buf[cur], gh2, W_ih2, b_ih2, 0, h2buf[1 - cur], (float*)nullptr);
    cur = 1 - cur;
  }
  for (int t = 0; t < T_DEC; ++t) {
    k_step_a<<<dim3(8, 8, 2), 256, 0, stream>>>(
        h1buf[cur], h2buf[cur], b_ih1, 0,
        W_hh1, b_hh1, W_hh2, b_hh2, h1buf[1 - cur], gh2);
    k_step_b<<<dim3(8, 8), 256, 0, stream>>>(
        h1buf[1 - cur], h2buf[cur], gh2, W_ih2, GW + (size_t)t * G3_, T_DEC * G3_,
        h2buf[1 - cur], h2seq + (size_t)t * HID_);
    cur = 1 - cur;
  }

  // logits = h2seq @ W_out^T + b_out  -> d_out rows m = b*27+t  (3456 x 20000 x 512)
  k_gemm<<<dim3((V_ + 127) / 128, (B_ * T_DEC) / 128), 256, 0, stream>>>(
      h2seq, HID_, W_out, HID_, 0, b_out, out, V_, V_, HID_);
  k_logsoftmax<<<B_ * T_DEC, 256, 0, stream>>>(out);
}